// Round 7
// baseline (706.128 us; speedup 1.0000x reference)
//
#include <hip/hip_runtime.h>

// Problem constants (from reference)
#define BN   8192
#define TN   128
#define HIDN 256
#define DTC  0.01f
// IN_DIM = 50: [ e(6) | e_dot(6) | xi(6) | mf(32) ], mf constant over t per b.

typedef float v2f __attribute__((ext_vector_type(2)));

// ---- forced VOP3P packed fp32 FMA (full-rate path; "v" pins arch VGPRs) ----
#define PK_FMA(d, a, w) \
    asm("v_pk_fma_f32 %0, %1, %2, %0" : "+v"(d) : "v"(a), "v"(w))
#define PK_FMA3(d, a, w, c) \
    asm("v_pk_fma_f32 %0, %1, %2, %3" : "=v"(d) : "v"(a), "v"(w), "v"(c))
#define SFMA(d, a, w) \
    asm("v_fma_f32 %0, %1, %2, %0" : "+v"(d) : "v"(a), "v"(w))

// ---- single-instruction DPP adds for the wave-64 sum ----
#define DPPADD_SHR(v, N) \
    asm volatile("v_add_f32_dpp %0, %0, %0 row_shr:" #N " row_mask:0xf bank_mask:0xf bound_ctrl:0" : "+v"(v))
#define DPPADD_BC15(v) \
    asm volatile("v_add_f32_dpp %0, %0, %0 row_bcast:15 row_mask:0xa bank_mask:0xf bound_ctrl:0" : "+v"(v))
#define DPPADD_BC31(v) \
    asm volatile("v_add_f32_dpp %0, %0, %0 row_bcast:31 row_mask:0xc bank_mask:0xf bound_ctrl:0" : "+v"(v))

#define LANE_SUM(v)  __int_as_float(__builtin_amdgcn_readlane(__float_as_int(v), 63))
#define RDLANE(v, l) __int_as_float(__builtin_amdgcn_readlane(__float_as_int(v), (l)))

// Ban AGPR allocation across this point: any value live across the loop body
// must then live in an arch VGPR (budget 512 via launch_bounds(256,1)), which
// kills the per-use v_accvgpr_read copy tax seen in rounds 1-6 (VGPR_Count
// stuck at 124 with ~132 AGPR-parked weights). Costs occupancy (1 wave/SIMD)
// -- acceptable: kernel is issue-bound with high ILP.
#define AGPR_BAN() asm volatile("" ::: \
    "a0","a1","a2","a3","a4","a5","a6","a7","a8","a9","a10","a11","a12","a13","a14","a15", \
    "a16","a17","a18","a19","a20","a21","a22","a23","a24","a25","a26","a27","a28","a29","a30","a31", \
    "a32","a33","a34","a35","a36","a37","a38","a39","a40","a41","a42","a43","a44","a45","a46","a47", \
    "a48","a49","a50","a51","a52","a53","a54","a55","a56","a57","a58","a59","a60","a61","a62","a63", \
    "a64","a65","a66","a67","a68","a69","a70","a71","a72","a73","a74","a75","a76","a77","a78","a79", \
    "a80","a81","a82","a83","a84","a85","a86","a87","a88","a89","a90","a91","a92","a93","a94","a95", \
    "a96","a97","a98","a99","a100","a101","a102","a103","a104","a105","a106","a107","a108","a109","a110","a111", \
    "a112","a113","a114","a115","a116","a117","a118","a119","a120","a121","a122","a123","a124","a125","a126","a127", \
    "a128","a129","a130","a131","a132","a133","a134","a135","a136","a137","a138","a139","a140","a141","a142","a143", \
    "a144","a145","a146","a147","a148","a149","a150","a151","a152","a153","a154","a155","a156","a157","a158","a159", \
    "a160","a161","a162","a163","a164","a165","a166","a167","a168","a169","a170","a171","a172","a173","a174","a175", \
    "a176","a177","a178","a179","a180","a181","a182","a183","a184","a185","a186","a187","a188","a189","a190","a191", \
    "a192","a193","a194","a195","a196","a197","a198","a199","a200","a201","a202","a203","a204","a205","a206","a207", \
    "a208","a209","a210","a211","a212","a213","a214","a215","a216","a217","a218","a219","a220","a221","a222","a223", \
    "a224","a225","a226","a227","a228","a229","a230","a231","a232","a233","a234","a235","a236","a237","a238","a239", \
    "a240","a241","a242","a243","a244","a245","a246","a247","a248","a249","a250","a251","a252","a253","a254","a255")

// One wave per batch element b. Lane L owns hidden units j = u*64+L, u=0..3,
// for BOTH MLPs. Inputs for 64 steps staged per-lane, broadcast via readlane.
__global__ __launch_bounds__(256, 1)
void visco_kernel(const float* __restrict__ e,    const float* __restrict__ ed,
                  const float* __restrict__ Earr, const float* __restrict__ nuarr,
                  const float* __restrict__ We,   const float* __restrict__ be,
                  const float* __restrict__ Wn,   const float* __restrict__ bn,
                  const float* __restrict__ Wen1, const float* __restrict__ ben1,
                  const float* __restrict__ Wen2, const float* __restrict__ ben2,
                  const float* __restrict__ Wd1,  const float* __restrict__ bd1,
                  const float* __restrict__ Wd2,  const float* __restrict__ bd2,
                  float* __restrict__ out)
{
    const int lane = threadIdx.x & 63;
    const int wv   = threadIdx.x >> 6;
    const int b    = (blockIdx.x << 2) + wv;   // 2048 blocks * 4 waves = 8192

    // ---- per-lane weight registers (K-pair layout) ----
    v2f   wP[2][4][9];   // wP[m][u][kk] = (W1[2kk][j], W1[2kk+1][j])
    v2f   cstP[2][4];    // {bias + mf-fold, 0} — pk-fma seed
    float w2s[4];        // Wen2[j]
    float w2k[4][6];     // Wd2[j][i]

    const float Eb  = Earr[b];
    const float nub = nuarr[b];

    #pragma unroll
    for (int u = 0; u < 4; ++u) {
        const int j = (u << 6) + lane;
        #pragma unroll
        for (int kk = 0; kk < 9; ++kk) {
            wP[0][u][kk] = v2f{Wen1[(2 * kk) * HIDN + j], Wen1[(2 * kk + 1) * HIDN + j]};
            wP[1][u][kk] = v2f{Wd1 [(2 * kk) * HIDN + j], Wd1 [(2 * kk + 1) * HIDN + j]};
        }
        float c0 = ben1[j];
        float c1 = bd1[j];
        #pragma unroll
        for (int k = 0; k < 16; ++k) {           // mf[0:16] = E*We + be
            const float m = fmaf(Eb, We[k], be[k]);
            c0 = fmaf(m, Wen1[(18 + k) * HIDN + j], c0);
            c1 = fmaf(m, Wd1 [(18 + k) * HIDN + j], c1);
        }
        #pragma unroll
        for (int k = 0; k < 16; ++k) {           // mf[16:32] = nu*Wn + bn
            const float m = fmaf(nub, Wn[k], bn[k]);
            c0 = fmaf(m, Wen1[(34 + k) * HIDN + j], c0);
            c1 = fmaf(m, Wd1 [(34 + k) * HIDN + j], c1);
        }
        cstP[0][u] = v2f{c0, 0.f};
        cstP[1][u] = v2f{c1, 0.f};
        w2s[u] = Wen2[j];
        #pragma unroll
        for (int i = 0; i < 6; ++i) w2k[u][i] = Wd2[j * 6 + i];
    }

    const float ben2v = ben2[0];
    float bd2v[6];
    #pragma unroll
    for (int i = 0; i < 6; ++i) bd2v[i] = bd2[i];

    // ---- state (uniform across lanes) + output streams ----
    v2f xi01 = v2f{0.f, 0.f}, xi23 = v2f{0.f, 0.f}, xi45 = v2f{0.f, 0.f};

    const float* eb = e  + (size_t)b * (TN * 6);
    const float* db = ed + (size_t)b * (TN * 6);
    float* outS = out + (size_t)b * TN;                            // stress [B,T]
    float* outX = out + (size_t)BN * TN + (size_t)b * (TN * 6);    // xi_all [B,T,6]

    for (int half = 0; half < 2; ++half) {
        // stage 64 steps: lane L holds features of step (half*64 + L)
        float sE[6], sD[6];
        const int base = ((half << 6) + lane) * 6;
        #pragma unroll
        for (int r = 0; r < 6; ++r) { sE[r] = eb[base + r]; sD[r] = db[base + r]; }

        #pragma unroll 2
        for (int t2 = 0; t2 < 64; ++t2) {
            AGPR_BAN();   // no loop-carried value may live in an AGPR

            const int t = (half << 6) + t2;

            // broadcast step t's inputs from lane t2 (pure VALU, no memory)
            const v2f x0 = v2f{RDLANE(sE[0], t2), RDLANE(sE[1], t2)};
            const v2f x1 = v2f{RDLANE(sE[2], t2), RDLANE(sE[3], t2)};
            const v2f x2 = v2f{RDLANE(sE[4], t2), RDLANE(sE[5], t2)};
            const v2f x3 = v2f{RDLANE(sD[0], t2), RDLANE(sD[1], t2)};
            const v2f x4 = v2f{RDLANE(sD[2], t2), RDLANE(sD[3], t2)};
            const v2f x5 = v2f{RDLANE(sD[4], t2), RDLANE(sD[5], t2)};

            float ps  = 0.f;
            float pk0 = 0.f, pk1 = 0.f, pk2 = 0.f, pk3 = 0.f, pk4 = 0.f, pk5 = 0.f;

            #pragma unroll
            for (int u = 0; u < 4; ++u) {
                v2f hp, gp;
                PK_FMA3(hp, x0, wP[0][u][0], cstP[0][u]);   // seed from cst
                PK_FMA3(gp, x0, wP[1][u][0], cstP[1][u]);
                PK_FMA(hp, x1,   wP[0][u][1]);  PK_FMA(gp, x1,   wP[1][u][1]);
                PK_FMA(hp, x2,   wP[0][u][2]);  PK_FMA(gp, x2,   wP[1][u][2]);
                PK_FMA(hp, x3,   wP[0][u][3]);  PK_FMA(gp, x3,   wP[1][u][3]);
                PK_FMA(hp, x4,   wP[0][u][4]);  PK_FMA(gp, x4,   wP[1][u][4]);
                PK_FMA(hp, x5,   wP[0][u][5]);  PK_FMA(gp, x5,   wP[1][u][5]);
                PK_FMA(hp, xi01, wP[0][u][6]);  PK_FMA(gp, xi01, wP[1][u][6]);
                PK_FMA(hp, xi23, wP[0][u][7]);  PK_FMA(gp, xi23, wP[1][u][7]);
                PK_FMA(hp, xi45, wP[0][u][8]);  PK_FMA(gp, xi45, wP[1][u][8]);

                const float h = fmaxf(hp.x + hp.y, 0.f);
                const float g = fmaxf(gp.x + gp.y, 0.f);
                SFMA(ps,  h, w2s[u]);
                SFMA(pk0, g, w2k[u][0]);
                SFMA(pk1, g, w2k[u][1]);
                SFMA(pk2, g, w2k[u][2]);
                SFMA(pk3, g, w2k[u][3]);
                SFMA(pk4, g, w2k[u][4]);
                SFMA(pk5, g, w2k[u][5]);
            }

            // wave-64 sum: 6 DPP stages, round-robin over the 7 values
            DPPADD_SHR(ps, 1);  DPPADD_SHR(pk0, 1); DPPADD_SHR(pk1, 1);
            DPPADD_SHR(pk2, 1); DPPADD_SHR(pk3, 1); DPPADD_SHR(pk4, 1); DPPADD_SHR(pk5, 1);
            DPPADD_SHR(ps, 2);  DPPADD_SHR(pk0, 2); DPPADD_SHR(pk1, 2);
            DPPADD_SHR(pk2, 2); DPPADD_SHR(pk3, 2); DPPADD_SHR(pk4, 2); DPPADD_SHR(pk5, 2);
            DPPADD_SHR(ps, 4);  DPPADD_SHR(pk0, 4); DPPADD_SHR(pk1, 4);
            DPPADD_SHR(pk2, 4); DPPADD_SHR(pk3, 4); DPPADD_SHR(pk4, 4); DPPADD_SHR(pk5, 4);
            DPPADD_SHR(ps, 8);  DPPADD_SHR(pk0, 8); DPPADD_SHR(pk1, 8);
            DPPADD_SHR(pk2, 8); DPPADD_SHR(pk3, 8); DPPADD_SHR(pk4, 8); DPPADD_SHR(pk5, 8);
            DPPADD_BC15(ps);  DPPADD_BC15(pk0); DPPADD_BC15(pk1);
            DPPADD_BC15(pk2); DPPADD_BC15(pk3); DPPADD_BC15(pk4); DPPADD_BC15(pk5);
            DPPADD_BC31(ps);  DPPADD_BC31(pk0); DPPADD_BC31(pk1);
            DPPADD_BC31(pk2); DPPADD_BC31(pk3); DPPADD_BC31(pk4); DPPADD_BC31(pk5);

            const float sS = LANE_SUM(ps);
            const float s0 = LANE_SUM(pk0);
            const float s1 = LANE_SUM(pk1);
            const float s2 = LANE_SUM(pk2);
            const float s3 = LANE_SUM(pk3);
            const float s4 = LANE_SUM(pk4);
            const float s5 = LANE_SUM(pk5);

            // emit xi BEFORE update, stress
            const float xw = (lane == 0) ? xi01.x :
                             (lane == 1) ? xi01.y :
                             (lane == 2) ? xi23.x :
                             (lane == 3) ? xi23.y :
                             (lane == 4) ? xi45.x : xi45.y;
            if (lane < 6)  outX[t * 6 + lane] = xw;
            if (lane == 6) outS[t] = sS + ben2v;

            // explicit Euler: xi += DT * (kin_sum + bd2)   (reference order)
            xi01.x = fmaf(DTC, s0 + bd2v[0], xi01.x);
            xi01.y = fmaf(DTC, s1 + bd2v[1], xi01.y);
            xi23.x = fmaf(DTC, s2 + bd2v[2], xi23.x);
            xi23.y = fmaf(DTC, s3 + bd2v[3], xi23.y);
            xi45.x = fmaf(DTC, s4 + bd2v[4], xi45.x);
            xi45.y = fmaf(DTC, s5 + bd2v[5], xi45.y);
        }
    }
}

extern "C" void kernel_launch(void* const* d_in, const int* in_sizes, int n_in,
                              void* d_out, int out_size, void* d_ws, size_t ws_size,
                              hipStream_t stream) {
    const float* e    = (const float*)d_in[0];
    const float* ed   = (const float*)d_in[1];
    const float* E    = (const float*)d_in[2];
    const float* nu   = (const float*)d_in[3];
    const float* We   = (const float*)d_in[4];
    const float* be   = (const float*)d_in[5];
    const float* Wn   = (const float*)d_in[6];
    const float* bn   = (const float*)d_in[7];
    const float* Wen1 = (const float*)d_in[8];
    const float* ben1 = (const float*)d_in[9];
    const float* Wen2 = (const float*)d_in[10];
    const float* ben2 = (const float*)d_in[11];
    const float* Wd1  = (const float*)d_in[12];
    const float* bd1  = (const float*)d_in[13];
    const float* Wd2  = (const float*)d_in[14];
    const float* bd2  = (const float*)d_in[15];
    float* out = (float*)d_out;

    dim3 grid(BN / 4);   // 4 waves (4 batch elems) per 256-thread block
    dim3 block(256);
    visco_kernel<<<grid, block, 0, stream>>>(e, ed, E, nu, We, be, Wn, bn,
                                             Wen1, ben1, Wen2, ben2,
                                             Wd1, bd1, Wd2, bd2, out);
}